// Round 2
// baseline (438.452 us; speedup 1.0000x reference)
//
#include <hip/hip_runtime.h>
#include <hip/hip_bf16.h>
#include <stdint.h>

#define B_ 16
#define C_ 256
#define O_ 256
#define H_ 64
#define W_ 64
#define HP 66
#define WP 66
#define HIDDEN 65
#define TEMP 34.0f

#define BM 128
#define BN 128
#define BK 32

typedef __bf16 bf16x8 __attribute__((ext_vector_type(8)));
typedef float floatx4 __attribute__((ext_vector_type(4)));
typedef unsigned int uint;
typedef unsigned short ushort;

__device__ __forceinline__ ushort f2bf(float f) {
    union { float f; uint32_t u; } v; v.f = f;
    uint32_t u = v.u;
    uint32_t r = (u + 0x7FFFu + ((u >> 16) & 1u)) >> 16;
    return (ushort)r;
}

// async global->LDS, 16 bytes per lane. LDS dest = wave-uniform base + lane*16.
typedef __attribute__((address_space(3))) void lds_void;
typedef const __attribute__((address_space(1))) void gbl_void;
__device__ __forceinline__ void glds16(const void* g, void* l) {
    __builtin_amdgcn_global_load_lds((gbl_void*)g, (lds_void*)l, 16, 0, 0);
}

// ---------------------------------------------------------------------------
// Kernel 1: NCHW fp32 -> zero-padded NHWC bf16 transpose, fused pooling.
// Grid 16*66 blocks, 256 threads. Vectorized: float4 in, uint4 out.
// ---------------------------------------------------------------------------
#define LTR 132   // uint row stride for the transpose tile (16B-aligned rows)
__global__ __launch_bounds__(256) void pad_pool_kernel(
    const float* __restrict__ x, ushort* __restrict__ xp,
    float* __restrict__ pooled)
{
    int b  = blockIdx.x / HP;
    int hp = blockIdx.x % HP;
    ushort* xpb = xp + ((size_t)(b * HP + hp)) * WP * C_;
    int tid = threadIdx.x;

    if (hp == 0 || hp == HP - 1) {               // border rows: all zero
        uint* p = (uint*)xpb;                    // 66*256/2 = 8448 uints
        for (int i = tid; i < WP * C_ / 2; i += 256) p[i] = 0;
        return;
    }
    int h = hp - 1;

    __shared__ uint  tr[64 * LTR];     // [w][c-pair], swizzled cols
    __shared__ float pr[8 * 256];      // pooling partials [w-group][c]

    // ---- load + transpose-in: thread (i): c-pair cp = i*16 + tid>>4, w-quad wq = tid&15
    int wq = tid & 15;
    int sw = (wq & 3) << 3;                      // col swizzle for this writer
    const float* xb = x + (((size_t)b * C_) * H_ + h) * W_ + wq * 4;
    #pragma unroll
    for (int i = 0; i < 8; i++) {
        int cp = i * 16 + (tid >> 4);
        const float* p0 = xb + (size_t)(2 * cp) * H_ * W_;
        float4 v0 = *(const float4*)p0;
        float4 v1 = *(const float4*)(p0 + H_ * W_);
        uint r0 = (uint)f2bf(v0.x) | ((uint)f2bf(v1.x) << 16);
        uint r1 = (uint)f2bf(v0.y) | ((uint)f2bf(v1.y) << 16);
        uint r2 = (uint)f2bf(v0.z) | ((uint)f2bf(v1.z) << 16);
        uint r3 = (uint)f2bf(v0.w) | ((uint)f2bf(v1.w) << 16);
        int col = cp ^ sw;
        tr[(wq * 4 + 0) * LTR + col] = r0;
        tr[(wq * 4 + 1) * LTR + col] = r1;
        tr[(wq * 4 + 2) * LTR + col] = r2;
        tr[(wq * 4 + 3) * LTR + col] = r3;
    }

    // zero padding columns wp=0 and wp=65 (32 uint4 each)
    if (tid < 32) {
        *(uint4*)(xpb + tid * 8) = uint4{0, 0, 0, 0};
    } else if (tid < 64) {
        *(uint4*)(xpb + (size_t)65 * C_ + (tid - 32) * 8) = uint4{0, 0, 0, 0};
    }
    __syncthreads();

    // ---- read rows + store uint4 + pooling partials
    int cg = tid & 31;                 // c-group (8 channels), fixed per thread
    int wg = tid >> 5;                 // w-group
    float acc[8] = {0, 0, 0, 0, 0, 0, 0, 0};
    #pragma unroll
    for (int i = 0; i < 8; i++) {
        int w = i * 8 + wg;
        int s = ((w >> 2) & 3) << 3;
        uint4 d = *(const uint4*)(&tr[w * LTR + ((cg * 4) ^ s)]);
        *(uint4*)(xpb + (size_t)(w + 1) * C_ + cg * 8) = d;
        acc[0] += __uint_as_float(d.x << 16);
        acc[1] += __uint_as_float(d.x & 0xffff0000u);
        acc[2] += __uint_as_float(d.y << 16);
        acc[3] += __uint_as_float(d.y & 0xffff0000u);
        acc[4] += __uint_as_float(d.z << 16);
        acc[5] += __uint_as_float(d.z & 0xffff0000u);
        acc[6] += __uint_as_float(d.w << 16);
        acc[7] += __uint_as_float(d.w & 0xffff0000u);
    }
    #pragma unroll
    for (int k = 0; k < 8; k++) pr[wg * 256 + cg * 8 + k] = acc[k];
    __syncthreads();

    float s = 0.f;
    #pragma unroll
    for (int j = 0; j < 8; j++) s += pr[j * 256 + tid];
    atomicAdd(&pooled[b * C_ + tid], s);
}

// ---------------------------------------------------------------------------
// Kernel 2: attention MLP + softmax. Single block.
// ---------------------------------------------------------------------------
__global__ void att_kernel(const float* __restrict__ pooled,
                           const float* __restrict__ w1,
                           const float* __restrict__ w2,
                           const float* __restrict__ b2,
                           float* __restrict__ att) {
    __shared__ float psh[B_ * C_];
    __shared__ float hsh[B_ * HIDDEN];
    int tid = threadIdx.x;
    for (int i = tid; i < B_ * C_; i += 256) psh[i] = pooled[i] * (1.0f / (H_ * W_));
    __syncthreads();
    for (int i = tid; i < B_ * HIDDEN; i += 256) {
        int b = i / HIDDEN, j = i % HIDDEN;
        float s = 0.f;
        for (int c = 0; c < C_; c++) s += psh[b * C_ + c] * w1[j * C_ + c];
        hsh[i] = fmaxf(s, 0.f);
    }
    __syncthreads();
    if (tid < B_) {
        float lg[4];
        float mx = -1e30f;
        for (int k = 0; k < 4; k++) {
            float s = b2[k];
            for (int j = 0; j < HIDDEN; j++) s += hsh[tid * HIDDEN + j] * w2[k * HIDDEN + j];
            lg[k] = s / TEMP;
            mx = fmaxf(mx, lg[k]);
        }
        float den = 0.f;
        for (int k = 0; k < 4; k++) { lg[k] = expf(lg[k] - mx); den += lg[k]; }
        for (int k = 0; k < 4; k++) att[tid * 4 + k] = lg[k] / den;
    }
}

// ---------------------------------------------------------------------------
// Kernel 3: aggregate weights -> bf16 [b][tap][o][c]. Packed uint stores.
// Grid 256 (o), 256 threads: cp = tid&127 (c-pair), bh = tid>>7 (batch half).
// ---------------------------------------------------------------------------
__global__ __launch_bounds__(256) void agg_kernel(
    const float* __restrict__ weight, const float* __restrict__ att,
    ushort* __restrict__ aggw)
{
    int o = blockIdx.x;
    int tid = threadIdx.x;
    int cp = tid & 127, bh = tid >> 7;
    __shared__ float a_sh[64];
    if (tid < 64) a_sh[tid] = att[tid];
    __syncthreads();

    float wv[4][18];
    #pragma unroll
    for (int k = 0; k < 4; k++) {
        const float* wp_ = weight + (((size_t)k * O_ + o) * C_ + cp * 2) * 9;
        #pragma unroll
        for (int t = 0; t < 18; t++) wv[k][t] = wp_[t];
    }
    uint* dst = (uint*)aggw;
    for (int b = bh * 8; b < bh * 8 + 8; b++) {
        float a0 = a_sh[b * 4 + 0], a1 = a_sh[b * 4 + 1];
        float a2 = a_sh[b * 4 + 2], a3 = a_sh[b * 4 + 3];
        #pragma unroll
        for (int t = 0; t < 9; t++) {
            float s0 = a0 * wv[0][t]     + a1 * wv[1][t]     + a2 * wv[2][t]     + a3 * wv[3][t];
            float s1 = a0 * wv[0][9 + t] + a1 * wv[1][9 + t] + a2 * wv[2][9 + t] + a3 * wv[3][9 + t];
            uint p = (uint)f2bf(s0) | ((uint)f2bf(s1) << 16);
            dst[(((size_t)b * 9 + t) * O_ + o) * (C_ / 2) + cp] = p;
        }
    }
}

// ---------------------------------------------------------------------------
// Kernel 4: conv as 9 shifted GEMMs, ty-grouped. global_load_lds staging,
// unpadded BK=32 LDS rows, 48 MFMA per barrier-pair, LDS-transpose epilogue.
// ---------------------------------------------------------------------------
__global__ __launch_bounds__(256, 4) void conv_kernel(
    const ushort* __restrict__ xp,    // [B][66][66][C] bf16
    const ushort* __restrict__ aggw,  // [B][9][O][C]  bf16
    float* __restrict__ out)          // [B][O][4096]  f32
{
    __shared__ union {
        struct {
            ushort A[3][BM * BK];      // 3 taps x [o 128][c 32]
            ushort Bst[2 * WP * BK];   // [prow 2][wp 66][c 32]
        } st;
        float scr[4 * 16 * 68];        // epilogue: 4 waves x [m 16][n 64 pad->68]
    } u;

    int bid = blockIdx.x;
    int b  = bid >> 6;
    int r  = bid & 63;
    int mt = r >> 5;
    int nt = r & 31;
    int tid = threadIdx.x;
    int h0 = nt * 2;

    int wave = tid >> 6, lane = tid & 63;
    int wr = (wave >> 1) * 64;
    int wc = (wave & 1) * 64;
    int fm = lane & 15;
    int q  = lane >> 4;

    // --- staging geometry (per-lane offsets; uniform bases kept scalar) ---
    int aoff_lane = (tid >> 2) * C_ + (tid & 3) * 8;       // A unit0 (row, col)
    const ushort* gA_base = aggw + ((size_t)(b * 9) * O_ + mt * BM) * C_;

    // B units v = ((prow*66)+wp)*4 + cc over [2][66][4]; thread handles v, v+256, (v+512 if tid<16)
    int v0 = tid, v1 = tid + 256, v2 = tid + 512;
    int pr0 = v0 / 264, re0 = v0 % 264;
    int pr1 = v1 / 264, re1 = v1 % 264;
    int pr2 = v2 / 264, re2 = v2 % 264;
    int boff0 = (pr0 * WP + (re0 >> 2)) * C_ + (re0 & 3) * 8;
    int boff1 = (pr1 * WP + (re1 >> 2)) * C_ + (re1 & 3) * 8;
    int boff2 = (pr2 * WP + (re2 >> 2)) * C_ + (re2 & 3) * 8;
    const ushort* gB_base = xp + ((size_t)b * HP + h0) * WP * C_;

    // --- fragment LDS offsets (ushort units) ---
    int aOff[4], bOff[4];
    int bRow = (wc >> 6) * (WP * BK);   // prow0 / prow1
    #pragma unroll
    for (int i = 0; i < 4; i++) {
        aOff[i] = (wr + i * 16 + fm) * BK + q * 8;
        bOff[i] = bRow + (i * 16 + fm) * BK + q * 8;
    }

    floatx4 acc[4][4] = {};

    for (int ty = 0; ty < 3; ty++) {
        const ushort* gA_ty = gA_base + (size_t)(ty * 3) * O_ * C_ + aoff_lane;
        const ushort* gB_ty = gB_base + (size_t)ty * WP * C_;
        for (int c0 = 0; c0 < C_; c0 += BK) {
            // stage A: 3 taps x 2 issues
            #pragma unroll
            for (int tt = 0; tt < 3; tt++) {
                const ushort* g = gA_ty + (size_t)tt * O_ * C_ + c0;
                glds16(g,            &u.st.A[tt][tid * 8]);
                glds16(g + 64 * C_,  &u.st.A[tt][(tid + 256) * 8]);
            }
            // stage B: 2 rows x 66 wp (528 units)
            glds16(gB_ty + boff0 + c0, &u.st.Bst[v0 * 8]);
            glds16(gB_ty + boff1 + c0, &u.st.Bst[v1 * 8]);
            if (tid < 16) glds16(gB_ty + boff2 + c0, &u.st.Bst[v2 * 8]);
            __syncthreads();

            #pragma unroll
            for (int tt = 0; tt < 3; tt++) {
                bf16x8 af[4], bv[4];
                #pragma unroll
                for (int i = 0; i < 4; i++) af[i] = *(const bf16x8*)(&u.st.A[tt][aOff[i]]);
                #pragma unroll
                for (int j = 0; j < 4; j++) bv[j] = *(const bf16x8*)(&u.st.Bst[bOff[j] + tt * BK]);
                #pragma unroll
                for (int i = 0; i < 4; i++)
                    #pragma unroll
                    for (int j = 0; j < 4; j++)
                        acc[i][j] = __builtin_amdgcn_mfma_f32_16x16x32_bf16(af[i], bv[j], acc[i][j], 0, 0, 0);
            }
            __syncthreads();
        }
    }

    // --- epilogue: per-wave LDS transpose -> float4 stores ---
    __syncthreads();   // staging buffers dead; scr aliases them
    float* outb = out + ((size_t)b * O_ + mt * BM) * (H_ * W_) + (size_t)nt * BN;
    float* myscr = u.scr + wave * (16 * 68);
    int mrow = lane >> 4;          // 0..3
    int n4 = lane & 15;
    #pragma unroll
    for (int i = 0; i < 4; i++) {
        #pragma unroll
        for (int j = 0; j < 4; j++)
            #pragma unroll
            for (int rr = 0; rr < 4; rr++)
                myscr[(q * 4 + rr) * 68 + j * 16 + fm] = acc[i][j][rr];
        // wave-private region; compiler inserts lgkm waits for the RAW
        #pragma unroll
        for (int mm = 0; mm < 4; mm++) {
            int m16 = mm * 4 + mrow;
            float4 d = *(const float4*)(&myscr[m16 * 68 + n4 * 4]);
            *(float4*)(&outb[(size_t)(wr + i * 16 + m16) * (H_ * W_) + wc + n4 * 4]) = d;
        }
    }
}

// ---------------------------------------------------------------------------
extern "C" void kernel_launch(void* const* d_in, const int* in_sizes, int n_in,
                              void* d_out, int out_size, void* d_ws, size_t ws_size,
                              hipStream_t stream) {
    const float* x      = (const float*)d_in[0];
    const float* weight = (const float*)d_in[1];
    const float* att_w1 = (const float*)d_in[2];
    const float* att_w2 = (const float*)d_in[3];
    const float* att_b2 = (const float*)d_in[4];
    float* out = (float*)d_out;

    char* ws = (char*)d_ws;
    float* pooled  = (float*)ws;                                  // 16 KiB
    float* att     = (float*)(ws + 16384);                        // 256 B
    ushort* aggw   = (ushort*)(ws + 32768);                       // 18,874,368 B
    ushort* xp     = (ushort*)(ws + 32768 + 18874368);            // 35,684,352 B

    hipMemsetAsync(pooled, 0, B_ * C_ * sizeof(float), stream);
    pad_pool_kernel<<<B_ * HP, 256, 0, stream>>>(x, xp, pooled);
    att_kernel<<<1, 256, 0, stream>>>(pooled, att_w1, att_w2, att_b2, att);
    agg_kernel<<<O_, 256, 0, stream>>>(weight, att, aggw);
    conv_kernel<<<B_ * 64, 256, 0, stream>>>(xp, aggw, out);
}

// Round 3
// 315.327 us; speedup vs baseline: 1.3905x; 1.3905x over previous
//
#include <hip/hip_runtime.h>
#include <hip/hip_bf16.h>
#include <stdint.h>

#define B_ 16
#define C_ 256
#define O_ 256
#define H_ 64
#define W_ 64
#define HP 66
#define WP 66
#define HIDDEN 65
#define TEMP 34.0f

#define BM 128
#define BN 128
#define BK 32

typedef __bf16 bf16x8 __attribute__((ext_vector_type(8)));
typedef float floatx4 __attribute__((ext_vector_type(4)));
typedef unsigned int uint;
typedef unsigned short ushort;

__device__ __forceinline__ ushort f2bf(float f) {
    union { float f; uint32_t u; } v; v.f = f;
    uint32_t u = v.u;
    uint32_t r = (u + 0x7FFFu + ((u >> 16) & 1u)) >> 16;
    return (ushort)r;
}

// async global->LDS, 16 bytes per lane. LDS dest = wave-uniform base + lane*16.
typedef __attribute__((address_space(3))) void lds_void;
typedef const __attribute__((address_space(1))) void gbl_void;
__device__ __forceinline__ void glds16(const void* g, void* l) {
    __builtin_amdgcn_global_load_lds((gbl_void*)g, (lds_void*)l, 16, 0, 0);
}

// ---------------------------------------------------------------------------
// Kernel 1: NCHW fp32 -> zero-padded NHWC bf16 transpose, fused pooling.
// ---------------------------------------------------------------------------
#define LTR 132   // uint row stride for the transpose tile (16B-aligned rows)
__global__ __launch_bounds__(256) void pad_pool_kernel(
    const float* __restrict__ x, ushort* __restrict__ xp,
    float* __restrict__ pooled)
{
    int b  = blockIdx.x / HP;
    int hp = blockIdx.x % HP;
    ushort* xpb = xp + ((size_t)(b * HP + hp)) * WP * C_;
    int tid = threadIdx.x;

    if (hp == 0 || hp == HP - 1) {               // border rows: all zero
        uint* p = (uint*)xpb;                    // 66*256/2 = 8448 uints
        for (int i = tid; i < WP * C_ / 2; i += 256) p[i] = 0;
        return;
    }
    int h = hp - 1;

    __shared__ uint  tr[64 * LTR];     // [w][c-pair], swizzled cols
    __shared__ float pr[8 * 256];      // pooling partials [w-group][c]

    int wq = tid & 15;
    int sw = (wq & 3) << 3;                      // col swizzle for this writer
    const float* xb = x + (((size_t)b * C_) * H_ + h) * W_ + wq * 4;
    #pragma unroll
    for (int i = 0; i < 8; i++) {
        int cp = i * 16 + (tid >> 4);
        const float* p0 = xb + (size_t)(2 * cp) * H_ * W_;
        float4 v0 = *(const float4*)p0;
        float4 v1 = *(const float4*)(p0 + H_ * W_);
        uint r0 = (uint)f2bf(v0.x) | ((uint)f2bf(v1.x) << 16);
        uint r1 = (uint)f2bf(v0.y) | ((uint)f2bf(v1.y) << 16);
        uint r2 = (uint)f2bf(v0.z) | ((uint)f2bf(v1.z) << 16);
        uint r3 = (uint)f2bf(v0.w) | ((uint)f2bf(v1.w) << 16);
        int col = cp ^ sw;
        tr[(wq * 4 + 0) * LTR + col] = r0;
        tr[(wq * 4 + 1) * LTR + col] = r1;
        tr[(wq * 4 + 2) * LTR + col] = r2;
        tr[(wq * 4 + 3) * LTR + col] = r3;
    }

    if (tid < 32) {
        *(uint4*)(xpb + tid * 8) = uint4{0, 0, 0, 0};
    } else if (tid < 64) {
        *(uint4*)(xpb + (size_t)65 * C_ + (tid - 32) * 8) = uint4{0, 0, 0, 0};
    }
    __syncthreads();

    int cg = tid & 31;
    int wg = tid >> 5;
    float acc[8] = {0, 0, 0, 0, 0, 0, 0, 0};
    #pragma unroll
    for (int i = 0; i < 8; i++) {
        int w = i * 8 + wg;
        int s = ((w >> 2) & 3) << 3;
        uint4 d = *(const uint4*)(&tr[w * LTR + ((cg * 4) ^ s)]);
        *(uint4*)(xpb + (size_t)(w + 1) * C_ + cg * 8) = d;
        acc[0] += __uint_as_float(d.x << 16);
        acc[1] += __uint_as_float(d.x & 0xffff0000u);
        acc[2] += __uint_as_float(d.y << 16);
        acc[3] += __uint_as_float(d.y & 0xffff0000u);
        acc[4] += __uint_as_float(d.z << 16);
        acc[5] += __uint_as_float(d.z & 0xffff0000u);
        acc[6] += __uint_as_float(d.w << 16);
        acc[7] += __uint_as_float(d.w & 0xffff0000u);
    }
    #pragma unroll
    for (int k = 0; k < 8; k++) pr[wg * 256 + cg * 8 + k] = acc[k];
    __syncthreads();

    float s = 0.f;
    #pragma unroll
    for (int j = 0; j < 8; j++) s += pr[j * 256 + tid];
    atomicAdd(&pooled[b * C_ + tid], s);
}

// ---------------------------------------------------------------------------
// Kernel 2: attention MLP + softmax. Single block.
// ---------------------------------------------------------------------------
__global__ void att_kernel(const float* __restrict__ pooled,
                           const float* __restrict__ w1,
                           const float* __restrict__ w2,
                           const float* __restrict__ b2,
                           float* __restrict__ att) {
    __shared__ float psh[B_ * C_];
    __shared__ float hsh[B_ * HIDDEN];
    int tid = threadIdx.x;
    for (int i = tid; i < B_ * C_; i += 256) psh[i] = pooled[i] * (1.0f / (H_ * W_));
    __syncthreads();
    for (int i = tid; i < B_ * HIDDEN; i += 256) {
        int b = i / HIDDEN, j = i % HIDDEN;
        float s = 0.f;
        for (int c = 0; c < C_; c++) s += psh[b * C_ + c] * w1[j * C_ + c];
        hsh[i] = fmaxf(s, 0.f);
    }
    __syncthreads();
    if (tid < B_) {
        float lg[4];
        float mx = -1e30f;
        for (int k = 0; k < 4; k++) {
            float s = b2[k];
            for (int j = 0; j < HIDDEN; j++) s += hsh[tid * HIDDEN + j] * w2[k * HIDDEN + j];
            lg[k] = s / TEMP;
            mx = fmaxf(mx, lg[k]);
        }
        float den = 0.f;
        for (int k = 0; k < 4; k++) { lg[k] = expf(lg[k] - mx); den += lg[k]; }
        for (int k = 0; k < 4; k++) att[tid * 4 + k] = lg[k] / den;
    }
}

// ---------------------------------------------------------------------------
// Kernel 3: aggregate weights -> bf16 [b][tap][o][c]. Packed uint stores.
// ---------------------------------------------------------------------------
__global__ __launch_bounds__(256) void agg_kernel(
    const float* __restrict__ weight, const float* __restrict__ att,
    ushort* __restrict__ aggw)
{
    int o = blockIdx.x;
    int tid = threadIdx.x;
    int cp = tid & 127, bh = tid >> 7;
    __shared__ float a_sh[64];
    if (tid < 64) a_sh[tid] = att[tid];
    __syncthreads();

    float wv[4][18];
    #pragma unroll
    for (int k = 0; k < 4; k++) {
        const float* wp_ = weight + (((size_t)k * O_ + o) * C_ + cp * 2) * 9;
        #pragma unroll
        for (int t = 0; t < 18; t++) wv[k][t] = wp_[t];
    }
    uint* dst = (uint*)aggw;
    for (int b = bh * 8; b < bh * 8 + 8; b++) {
        float a0 = a_sh[b * 4 + 0], a1 = a_sh[b * 4 + 1];
        float a2 = a_sh[b * 4 + 2], a3 = a_sh[b * 4 + 3];
        #pragma unroll
        for (int t = 0; t < 9; t++) {
            float s0 = a0 * wv[0][t]     + a1 * wv[1][t]     + a2 * wv[2][t]     + a3 * wv[3][t];
            float s1 = a0 * wv[0][9 + t] + a1 * wv[1][9 + t] + a2 * wv[2][9 + t] + a3 * wv[3][9 + t];
            uint p = (uint)f2bf(s0) | ((uint)f2bf(s1) << 16);
            dst[(((size_t)b * 9 + t) * O_ + o) * (C_ / 2) + cp] = p;
        }
    }
}

// ---------------------------------------------------------------------------
// Kernel 4: conv as 9 shifted GEMMs (ty-grouped, 48 MFMA per barrier-pair).
// global_load_lds staging with XOR-swizzled 16B chunks:
//   chunk (row, q) stored at row*64B + (q ^ ((row>>1)&3))*16B
// -> ds_read_b128 fragment reads are bank-conflict-free (8 consecutive lanes
//    span all eight 4-bank groups), while keeping the lane-contiguous LDS
//    destination that global_load_lds requires.
// ---------------------------------------------------------------------------
__global__ __launch_bounds__(256, 4) void conv_kernel(
    const ushort* __restrict__ xp,    // [B][66][66][C] bf16
    const ushort* __restrict__ aggw,  // [B][9][O][C]  bf16
    float* __restrict__ out)          // [B][O][4096]  f32
{
    __shared__ union {
        struct {
            ushort A[3][BM * BK];      // 3 taps x [o 128][c 32] (chunk-swizzled)
            ushort Bst[2 * WP * BK];   // [prow 2][wp 66][c 32] (chunk-swizzled)
        } st;
        float scr[4 * 16 * 68];        // epilogue transpose scratch
    } u;

    int bid = blockIdx.x;
    int b  = bid >> 6;
    int r  = bid & 63;
    int mt = r >> 5;
    int nt = r & 31;
    int tid = threadIdx.x;
    int h0 = nt * 2;

    int wave = tid >> 6, lane = tid & 63;
    int wr = (wave >> 1) * 64;
    int wc = (wave & 1) * 64;
    int fm = lane & 15;
    int q  = lane >> 4;

    // --- staging source offsets (swizzle-permuted per-lane columns) ---
    int rowA = tid >> 2;
    int ccA  = (tid & 3) ^ ((tid >> 3) & 3);
    int aoff_lane = rowA * C_ + ccA * 8;
    const ushort* gA_base = aggw + ((size_t)(b * 9) * O_ + mt * BM) * C_;

    int v0 = tid, v1 = tid + 256, v2 = tid + 512;   // B chunk units, 528 total
    int rB0 = v0 >> 2, rB1 = v1 >> 2, rB2 = v2 >> 2;
    int pr0 = 0;
    int pr1 = (rB1 >= 66) ? 1 : 0;
    int pr2 = 1;
    int boff0 = (pr0 * WP + rB0) * C_            + (((v0 & 3) ^ ((v0 >> 3) & 3)) * 8);
    int boff1 = (pr1 * WP + (rB1 - pr1 * 66)) * C_ + (((v1 & 3) ^ ((v1 >> 3) & 3)) * 8);
    int boff2 = (pr2 * WP + (rB2 - 66)) * C_     + (((v2 & 3) ^ ((v2 >> 3) & 3)) * 8);
    const ushort* gB_base = xp + ((size_t)b * HP + h0) * WP * C_;

    // --- fragment LDS offsets (ushort units, c0-invariant, swizzled) ---
    int aOffL[4];
    int aswz = (q ^ ((fm >> 1) & 3)) * 8;      // row bits below 16 come only from fm
    #pragma unroll
    for (int i = 0; i < 4; i++)
        aOffL[i] = (wr + i * 16 + fm) * BK + aswz;

    int prB = wc >> 6;
    int boffL[3][4];
    #pragma unroll
    for (int tt = 0; tt < 3; tt++)
        #pragma unroll
        for (int j = 0; j < 4; j++) {
            int rr = prB * 66 + j * 16 + fm + tt;
            boffL[tt][j] = rr * BK + ((q ^ ((rr >> 1) & 3)) * 8);
        }

    floatx4 acc[4][4] = {};

    for (int ty = 0; ty < 3; ty++) {
        const ushort* gA_ty = gA_base + (size_t)(ty * 3) * O_ * C_ + aoff_lane;
        const ushort* gB_ty = gB_base + (size_t)ty * WP * C_;
        for (int c0 = 0; c0 < C_; c0 += BK) {
            #pragma unroll
            for (int tt = 0; tt < 3; tt++) {
                const ushort* g = gA_ty + (size_t)tt * O_ * C_ + c0;
                glds16(g,            &u.st.A[tt][tid * 8]);
                glds16(g + 64 * C_,  &u.st.A[tt][(tid + 256) * 8]);
            }
            glds16(gB_ty + boff0 + c0, &u.st.Bst[v0 * 8]);
            glds16(gB_ty + boff1 + c0, &u.st.Bst[v1 * 8]);
            if (tid < 16) glds16(gB_ty + boff2 + c0, &u.st.Bst[v2 * 8]);
            __syncthreads();

            #pragma unroll
            for (int tt = 0; tt < 3; tt++) {
                bf16x8 af[4], bv[4];
                #pragma unroll
                for (int i = 0; i < 4; i++) af[i] = *(const bf16x8*)(&u.st.A[tt][aOffL[i]]);
                #pragma unroll
                for (int j = 0; j < 4; j++) bv[j] = *(const bf16x8*)(&u.st.Bst[boffL[tt][j]]);
                #pragma unroll
                for (int i = 0; i < 4; i++)
                    #pragma unroll
                    for (int j = 0; j < 4; j++)
                        acc[i][j] = __builtin_amdgcn_mfma_f32_16x16x32_bf16(af[i], bv[j], acc[i][j], 0, 0, 0);
            }
            __syncthreads();
        }
    }

    // --- epilogue: per-wave LDS transpose -> float4 stores ---
    __syncthreads();   // staging buffers dead; scr aliases them
    float* outb = out + ((size_t)b * O_ + mt * BM) * (H_ * W_) + (size_t)nt * BN;
    float* myscr = u.scr + wave * (16 * 68);
    int mrow = lane >> 4;
    int n4 = lane & 15;
    #pragma unroll
    for (int i = 0; i < 4; i++) {
        #pragma unroll
        for (int j = 0; j < 4; j++)
            #pragma unroll
            for (int rr = 0; rr < 4; rr++)
                myscr[(q * 4 + rr) * 68 + j * 16 + fm] = acc[i][j][rr];
        #pragma unroll
        for (int mm = 0; mm < 4; mm++) {
            int m16 = mm * 4 + mrow;
            float4 d = *(const float4*)(&myscr[m16 * 68 + n4 * 4]);
            *(float4*)(&outb[(size_t)(wr + i * 16 + m16) * (H_ * W_) + wc + n4 * 4]) = d;
        }
    }
}

// ---------------------------------------------------------------------------
extern "C" void kernel_launch(void* const* d_in, const int* in_sizes, int n_in,
                              void* d_out, int out_size, void* d_ws, size_t ws_size,
                              hipStream_t stream) {
    const float* x      = (const float*)d_in[0];
    const float* weight = (const float*)d_in[1];
    const float* att_w1 = (const float*)d_in[2];
    const float* att_w2 = (const float*)d_in[3];
    const float* att_b2 = (const float*)d_in[4];
    float* out = (float*)d_out;

    char* ws = (char*)d_ws;
    float* pooled  = (float*)ws;                                  // 16 KiB
    float* att     = (float*)(ws + 16384);                        // 256 B
    ushort* aggw   = (ushort*)(ws + 32768);                       // 18,874,368 B
    ushort* xp     = (ushort*)(ws + 32768 + 18874368);            // 35,684,352 B

    hipMemsetAsync(pooled, 0, B_ * C_ * sizeof(float), stream);
    pad_pool_kernel<<<B_ * HP, 256, 0, stream>>>(x, xp, pooled);
    att_kernel<<<1, 256, 0, stream>>>(pooled, att_w1, att_w2, att_b2, att);
    agg_kernel<<<O_, 256, 0, stream>>>(weight, att, aggw);
    conv_kernel<<<B_ * 64, 256, 0, stream>>>(xp, aggw, out);
}